// Round 1
// 211.951 us; speedup vs baseline: 1.0038x; 1.0038x over previous
//
#include <hip/hip_runtime.h>

#define B_ 32
#define CI 128
#define CO 256
#define K_DIM 1152            // 9*128
#define M_DIM 100352          // 32*56*56
#define BM 128
#define BN 256
#define BK 32
#define KTILES 36
#define NBUF 3                // 3-deep LDS pipeline (stage t+2 while computing t)
#define HPAD 58               // 56 + halo
#define XB_OFF 589824         // byte offset of xb in ws (after wt: 1152*256*2 B)
#define WTBLK 72              // (K_DIM/64)*(CO/64) transpose tiles
#define XPBLK 6728            // (B_*HPAD*HPAD*16)/256 pad blocks

typedef float          floatx4  __attribute__((ext_vector_type(4)));
typedef unsigned short ushortx8 __attribute__((ext_vector_type(8)));
typedef __bf16         bf16x8   __attribute__((ext_vector_type(8)));

typedef __attribute__((address_space(1))) void gas_void;
typedef __attribute__((address_space(3))) void las_void;
#define GLD16(g, l) __builtin_amdgcn_global_load_lds( \
    (gas_void*)(uintptr_t)(g), (las_void*)(l), 16, 0, 0)

__device__ __forceinline__ unsigned short bf16_rne(float f) {
    unsigned u = __builtin_bit_cast(unsigned, f);
    u += 0x7FFFu + ((u >> 16) & 1u);
    return (unsigned short)(u >> 16);
}

// ---- fused prepass: blocks [0,72) transpose w -> wt bf16 [256][1152];
//      blocks [72, 72+6728) pad x -> xb bf16 [32][58][58][128] with zero halo.
//      Fusing overlaps the tiny latency-bound transpose with the pad pass.
__global__ void prepass_kernel(const float* __restrict__ x,
                               const float* __restrict__ w,
                               unsigned short* __restrict__ xb,
                               unsigned short* __restrict__ wt) {
    __shared__ unsigned short tile[64][65];
    if (blockIdx.x < WTBLK) {
        const int kt = (blockIdx.x % 18) * 64, nt = (blockIdx.x / 18) * 64;
        #pragma unroll
        for (int i = 0; i < 16; ++i) {
            int idx = i * 256 + threadIdx.x;
            int kl = idx >> 6, nl = idx & 63;
            tile[kl][nl] = bf16_rne(w[(size_t)(kt + kl) * CO + nt + nl]);
        }
        __syncthreads();
        #pragma unroll
        for (int i = 0; i < 16; ++i) {
            int idx = i * 256 + threadIdx.x;
            int nl = idx >> 6, kl = idx & 63;
            wt[(size_t)(nt + nl) * K_DIM + kt + kl] = tile[kl][nl];
        }
    } else {
        const int t   = (blockIdx.x - WTBLK) * 256 + threadIdx.x;
        const int pix = t >> 4;
        const int cc  = (t & 15) << 3;
        const int b   = pix / (HPAD * HPAD);
        const int rem = pix % (HPAD * HPAD);
        const int hp  = rem / HPAD, wp = rem % HPAD;
        ushortx8 g = {0, 0, 0, 0, 0, 0, 0, 0};
        if (hp >= 1 && hp <= 56 && wp >= 1 && wp <= 56) {
            const float* s = x + ((size_t)((b * 56 + hp - 1) * 56 + (wp - 1))) * CI + cc;
            floatx4 f0 = ((const floatx4*)s)[0];
            floatx4 f1 = ((const floatx4*)s)[1];
            #pragma unroll
            for (int e = 0; e < 4; ++e) { g[e] = bf16_rne(f0[e]); g[e + 4] = bf16_rne(f1[e]); }
        }
        *(ushortx8*)(xb + (size_t)pix * CI + cc) = g;
    }
}

// ---- main: implicit-GEMM conv, BM=128 BN=256, 8 waves.
// Schedule: 3-buffer counted-vmcnt pipeline (T3+T4): stage tile t+2 while
// computing tile t; one raw s_barrier per K-tile; s_waitcnt vmcnt(3) keeps
// the newest stage's 3 global_load_lds in flight across the barrier (never
// drain to 0 until the tail). Replaces __syncthreads()'s vmcnt(0) drain that
// capped MfmaUtil at 27%.
// launch_bounds(512,4): 128 regs/lane budget -- MUST hold ~56 VGPR + 64 AGPR.
__global__ __launch_bounds__(512, 4)
void conv_gemm_kernel(const unsigned short* __restrict__ xb,
                      const unsigned short* __restrict__ wt,
                      const float* __restrict__ bias,
                      float* __restrict__ out) {
    __shared__ unsigned short As[NBUF][BM * BK];   // 3 x 8 KB, packed, chunk-swizzled
    __shared__ unsigned short Bs[NBUF][BN * BK];   // 3 x 16 KB   (total 72 KB -> 2 blocks/CU)

    const int tid  = threadIdx.x;
    const int by   = blockIdx.x;             // m tile 0..783 (full N per block)
    const int wid  = tid >> 6;               // 0..7
    const int lane = tid & 63;
    const int lrow = lane & 15;
    const int quad = lane >> 4;
    const int wm   = (wid & 1) * 64;
    const int wn   = (wid >> 1) * 64;        // 0,64,128,192

    // staging: lane l -> LDS slot l (16 B) = seg-row l>>2, pos l&3; fetches
    // global chunk (pos - (row>>1)) & 3   (rotation swizzle; 0 conflicts)
    const int rseg = lane >> 2;
    const int cglb = ((lane & 3) - (rseg >> 1)) & 3;

    // A: 128 rows staged by 8 waves, 16 rows/wave, 1 GLD16/thread
    const int ar = wid * 16 + rseg;
    const int m0 = by * BM + ar;
    const int b0 = m0 / 3136, r0 = m0 % 3136;
    const unsigned short* ag0 = xb + ((size_t)((b0 * HPAD + r0 / 56) * HPAD + r0 % 56)) * CI + cglb * 8;

    // B: 256 rows staged by 8 waves, 32 rows/wave, 2 GLD16/thread
    const int nr0 = wid * 32 + rseg;
    const unsigned short* bg0 = wt + (size_t)nr0 * K_DIM + cglb * 8;
    const unsigned short* bg1 = bg0 + (size_t)16 * K_DIM;

    const int ldsA  = (wid * 16) * BK;       // element offsets within a buffer
    const int ldsB0 = (wid * 32) * BK;
    const int ldsB1 = ldsB0 + 16 * BK;

    // fragment read offsets
    const int swz = ((quad + (lrow >> 1)) & 3) * 8;
    int a_idx[4], b_idx[4];
    #pragma unroll
    for (int i = 0; i < 4; ++i) {
        a_idx[i] = (wm + i * 16 + lrow) * BK + swz;
        b_idx[i] = (wn + i * 16 + lrow) * BK + swz;
    }

    floatx4 acc[4][4] = {};

    auto stage = [&](int kb, int buf) {
        const int p    = kb >> 2;                       // patch 0..8
        const int c0   = (kb & 3) << 5;
        const int aoff = (p / 3 * HPAD + p % 3) * CI + c0;
        const int boff = kb * BK;
        GLD16(ag0 + aoff, &As[buf][ldsA]);
        GLD16(bg0 + boff, &Bs[buf][ldsB0]);
        GLD16(bg1 + boff, &Bs[buf][ldsB1]);
    };

    auto compute = [&](int buf) {
        ushortx8 arv[4], brv[4];
        #pragma unroll
        for (int mi = 0; mi < 4; ++mi) arv[mi] = *(const ushortx8*)&As[buf][a_idx[mi]];
        #pragma unroll
        for (int ni = 0; ni < 4; ++ni) brv[ni] = *(const ushortx8*)&Bs[buf][b_idx[ni]];
        __builtin_amdgcn_s_setprio(1);
        #pragma unroll
        for (int mi = 0; mi < 4; ++mi)
            #pragma unroll
            for (int ni = 0; ni < 4; ++ni)
                acc[mi][ni] = __builtin_amdgcn_mfma_f32_16x16x32_bf16(
                    __builtin_bit_cast(bf16x8, arv[mi]),
                    __builtin_bit_cast(bf16x8, brv[ni]),
                    acc[mi][ni], 0, 0, 0);
        __builtin_amdgcn_s_setprio(0);
    };

    // prologue: tiles 0,1 in flight (6 loads outstanding per wave)
    stage(0, 0);
    stage(1, 1);

    // Per K-tile: wait until tile t's 3 loads landed (leave newest stage's 3
    // in flight), barrier (all waves agree => whole tile resident; also all
    // waves have consumed tile t-1, so staging t+2 into buf (t-1)%3 is safe),
    // then issue stage(t+2), ds_read frags of t, 16 MFMA.
#define ITER(T, BC, BS)                                                  \
    do {                                                                 \
        if ((T) < KTILES - 1) asm volatile("s_waitcnt vmcnt(3)" ::: "memory"); \
        else                  asm volatile("s_waitcnt vmcnt(0)" ::: "memory"); \
        __builtin_amdgcn_s_barrier();                                    \
        asm volatile("" ::: "memory");                                   \
        if ((T) + 2 < KTILES) stage((T) + 2, (BS));                      \
        compute((BC));                                                   \
    } while (0)

    #pragma unroll 1
    for (int tt = 0; tt < KTILES; tt += 3) {
        ITER(tt + 0, 0, 2);
        ITER(tt + 1, 1, 0);
        ITER(tt + 2, 2, 1);
    }
#undef ITER

    // epilogue: bias + store (C/D: col=lane&15, row=quad*4+r)
    float bv[4];
    #pragma unroll
    for (int ni = 0; ni < 4; ++ni)
        bv[ni] = bias[wn + ni * 16 + lrow];

    #pragma unroll
    for (int mi = 0; mi < 4; ++mi) {
        #pragma unroll
        for (int r = 0; r < 4; ++r) {
            const int row = by * BM + wm + mi * 16 + quad * 4 + r;
            float* o = out + (size_t)row * CO + wn + lrow;
            #pragma unroll
            for (int ni = 0; ni < 4; ++ni)
                o[ni * 16] = acc[mi][ni][r] + bv[ni];
        }
    }
}

extern "C" void kernel_launch(void* const* d_in, const int* in_sizes, int n_in,
                              void* d_out, int out_size, void* d_ws, size_t ws_size,
                              hipStream_t stream) {
    (void)in_sizes; (void)n_in; (void)out_size; (void)ws_size;
    const float* x    = (const float*)d_in[0];
    const float* w    = (const float*)d_in[1];
    const float* bias = (const float*)d_in[2];
    float* out = (float*)d_out;

    unsigned short* wt = (unsigned short*)d_ws;                     // bf16 [256][1152]
    unsigned short* xb = (unsigned short*)((char*)d_ws + XB_OFF);   // bf16 [32][58][58][128]

    prepass_kernel<<<dim3(WTBLK + XPBLK), dim3(256), 0, stream>>>(x, w, xb, wt);
    conv_gemm_kernel<<<dim3(M_DIM / BM), dim3(512), 0, stream>>>(xb, wt, bias, out);
}

// Round 2
// 204.681 us; speedup vs baseline: 1.0394x; 1.0355x over previous
//
#include <hip/hip_runtime.h>

#define B_ 32
#define CI 128
#define CO 256
#define K_DIM 1152            // 9*128
#define M_DIM 100352          // 32*56*56
#define BM 256
#define BN 256
#define BK 64
#define KT 18                 // K_DIM / BK
#define HPAD 58               // 56 + halo
#define XB_OFF 589824         // byte offset of xb in ws (after wt: 1152*256*2 B)
#define WTBLK 72              // (K_DIM/64)*(CO/64) transpose tiles
#define XPBLK 6728            // (B_*HPAD*HPAD*16)/256 pad blocks
#define GRID_M 392            // M_DIM / BM = 49*8 (divisible by 8 XCDs)

typedef float          floatx4  __attribute__((ext_vector_type(4)));
typedef unsigned short ushortx8 __attribute__((ext_vector_type(8)));
typedef __bf16         bf16x8   __attribute__((ext_vector_type(8)));

typedef __attribute__((address_space(1))) void gas_void;
typedef __attribute__((address_space(3))) void las_void;
#define GLD16(g, l) __builtin_amdgcn_global_load_lds( \
    (gas_void*)(uintptr_t)(g), (las_void*)(l), 16, 0, 0)

__device__ __forceinline__ unsigned short bf16_rne(float f) {
    unsigned u = __builtin_bit_cast(unsigned, f);
    u += 0x7FFFu + ((u >> 16) & 1u);
    return (unsigned short)(u >> 16);
}

// ---- fused prepass: blocks [0,72) transpose w -> wt bf16 [256][1152];
//      blocks [72, 72+6728) pad x -> xb bf16 [32][58][58][128] with zero halo.
__global__ void prepass_kernel(const float* __restrict__ x,
                               const float* __restrict__ w,
                               unsigned short* __restrict__ xb,
                               unsigned short* __restrict__ wt) {
    __shared__ unsigned short tile[64][65];
    if (blockIdx.x < WTBLK) {
        const int kt = (blockIdx.x % 18) * 64, nt = (blockIdx.x / 18) * 64;
        #pragma unroll
        for (int i = 0; i < 16; ++i) {
            int idx = i * 256 + threadIdx.x;
            int kl = idx >> 6, nl = idx & 63;
            tile[kl][nl] = bf16_rne(w[(size_t)(kt + kl) * CO + nt + nl]);
        }
        __syncthreads();
        #pragma unroll
        for (int i = 0; i < 16; ++i) {
            int idx = i * 256 + threadIdx.x;
            int nl = idx >> 6, kl = idx & 63;
            wt[(size_t)(nt + nl) * K_DIM + kt + kl] = tile[kl][nl];
        }
    } else {
        const int t   = (blockIdx.x - WTBLK) * 256 + threadIdx.x;
        const int pix = t >> 4;
        const int cc  = (t & 15) << 3;
        const int b   = pix / (HPAD * HPAD);
        const int rem = pix % (HPAD * HPAD);
        const int hp  = rem / HPAD, wp = rem % HPAD;
        ushortx8 g = {0, 0, 0, 0, 0, 0, 0, 0};
        if (hp >= 1 && hp <= 56 && wp >= 1 && wp <= 56) {
            const float* s = x + ((size_t)((b * 56 + hp - 1) * 56 + (wp - 1))) * CI + cc;
            floatx4 f0 = ((const floatx4*)s)[0];
            floatx4 f1 = ((const floatx4*)s)[1];
            #pragma unroll
            for (int e = 0; e < 4; ++e) { g[e] = bf16_rne(f0[e]); g[e + 4] = bf16_rne(f1[e]); }
        }
        *(ushortx8*)(xb + (size_t)pix * CI + cc) = g;
    }
}

// ---- main: implicit-GEMM conv, 256x256 tile, BK=64, 8-phase-style schedule.
// Per K-tile: 4 phases {barrier; ds_read one subtile; issue one 16KB half-stage
// (2 GLD16/thread); 16 MFMA under setprio}. vmcnt(4) checkpoints only at P0/P2
// (2 half-stages always in flight; never drained to 0 until the tail).
// LDS: 2 buf x 2 K-half planes x ([256][32] bf16) for A and B = 128 KB.
// Packed 64B rows keep the measured-zero-conflict rotation swizzle:
//   staging lane l -> slot (l&3); fetches global chunk ((l&3)-(rseg>>1))&3,
//   reader at row%16==lrow uses chunk (quad+(lrow>>1))&3  -> retrieves chunk==quad.
// launch_bounds(512,2): 256-reg budget holds acc 8x4x4=128 + frags + addr.
__global__ __launch_bounds__(512, 2)
void conv_gemm_kernel(const unsigned short* __restrict__ xb,
                      const unsigned short* __restrict__ wt,
                      const float* __restrict__ bias,
                      float* __restrict__ out) {
    __shared__ unsigned short As[2][2][BM * 32];   // [buf][kk][row*32+chunk], 4 x 16 KB
    __shared__ unsigned short Bs[2][2][BN * 32];   // 4 x 16 KB   (total 128 KB)

    const int tid  = threadIdx.x;
    const int bid  = blockIdx.x;
    const int by   = (bid & 7) * (GRID_M / 8) + (bid >> 3);  // XCD-contiguous m-tiles
    const int wid  = tid >> 6;               // 0..7
    const int lane = tid & 63;
    const int lrow = lane & 15;
    const int quad = lane >> 4;
    const int wm   = (wid & 1) * 128;        // wave rows: 128 of 256
    const int wn   = (wid >> 1) * 64;        // wave cols: 64 of 256

    // staging lane mapping (verified): seg-row = lane>>2, slot = lane&3,
    // fetch global chunk (slot - (rseg>>1)) & 3
    const int rseg = lane >> 2;
    const int cglb = ((lane & 3) - (rseg >> 1)) & 3;

    // global row bases for the two 128-row GLD rounds
    const unsigned short* aga[2];
    const unsigned short* bga[2];
    #pragma unroll
    for (int g = 0; g < 2; ++g) {
        const int m0 = by * BM + g * 128 + wid * 16 + rseg;
        const int b0 = m0 / 3136, r0 = m0 % 3136;
        aga[g] = xb + ((size_t)((b0 * HPAD + r0 / 56) * HPAD + r0 % 56)) * CI + cglb * 8;
        const int n0 = g * 128 + wid * 16 + rseg;
        bga[g] = wt + (size_t)n0 * K_DIM + cglb * 8;
    }
    const int wbase = wid * 512;             // (wid*16)*32 elements within a plane

    // fragment read offsets within a [256][32] plane
    const int swz = ((quad + (lrow >> 1)) & 3) * 8;
    int arow[8], brow[4];
    #pragma unroll
    for (int i = 0; i < 8; ++i) arow[i] = (wm + i * 16 + lrow) * 32 + swz;
    #pragma unroll
    for (int i = 0; i < 4; ++i) brow[i] = (wn + i * 16 + lrow) * 32 + swz;

    floatx4 acc[8][4] = {};

    auto stageA = [&](int t1, int kk, int sb) {      // one 16 KB A K-half of tile t1
        const int p    = t1 >> 1;                    // patch 0..8
        const int aoff = (p / 3 * HPAD + p % 3) * CI + (t1 & 1) * 64 + kk * 32;
        GLD16(aga[0] + aoff, &As[sb][kk][wbase]);
        GLD16(aga[1] + aoff, &As[sb][kk][4096 + wbase]);
    };
    auto stageB = [&](int t1, int kk, int sb) {      // one 16 KB B K-half of tile t1
        const int boff = t1 * 64 + kk * 32;
        GLD16(bga[0] + boff, &Bs[sb][kk][wbase]);
        GLD16(bga[1] + boff, &Bs[sb][kk][4096 + wbase]);
    };

    ushortx8 bfr[4], afr[4];
    auto rdB = [&](int buf, int kk) {
        #pragma unroll
        for (int ni = 0; ni < 4; ++ni) bfr[ni] = *(const ushortx8*)&Bs[buf][kk][brow[ni]];
    };
    auto rdA = [&](int buf, int kk, int h) {
        #pragma unroll
        for (int i = 0; i < 4; ++i) afr[i] = *(const ushortx8*)&As[buf][kk][arow[h * 4 + i]];
    };
    auto mm = [&](int h) {
        __builtin_amdgcn_s_setprio(1);
        #pragma unroll
        for (int i = 0; i < 4; ++i)
            #pragma unroll
            for (int ni = 0; ni < 4; ++ni)
                acc[h * 4 + i][ni] = __builtin_amdgcn_mfma_f32_16x16x32_bf16(
                    __builtin_bit_cast(bf16x8, afr[i]),
                    __builtin_bit_cast(bf16x8, bfr[ni]),
                    acc[h * 4 + i][ni], 0, 0, 0);
        __builtin_amdgcn_s_setprio(0);
    };

    // prologue: tile 0's 4 half-stages into buf 0 (issue order = steady state)
    stageA(0, 0, 0); stageB(0, 0, 0); stageA(0, 1, 0); stageB(0, 1, 0);

    #pragma unroll 1
    for (int t = 0; t < KT; ++t) {
        const int buf  = t & 1, sb = buf ^ 1;
        const int t1   = t + 1;
        const bool more = t1 < KT;
        // P0: kk0 / mi 0-3. Checkpoint confirms A-k0,B-k0 of tile t
        //     (issued 4 and 3 half-stages ago; leaves A-k1,B-k1 in flight).
        asm volatile("s_waitcnt vmcnt(4)\n\ts_barrier" ::: "memory");
        rdB(buf, 0); rdA(buf, 0, 0);
        if (more) stageA(t1, 0, sb);
        mm(0);
        // P1: kk0 / mi 4-7 (reuses bfr)
        asm volatile("s_barrier" ::: "memory");
        rdA(buf, 0, 1);
        if (more) stageB(t1, 0, sb);
        mm(1);
        // P2: kk1 / mi 0-3. Checkpoint confirms A-k1,B-k1 of tile t.
        if (more) asm volatile("s_waitcnt vmcnt(4)\n\ts_barrier" ::: "memory");
        else      asm volatile("s_waitcnt vmcnt(0)\n\ts_barrier" ::: "memory");
        rdB(buf, 1); rdA(buf, 1, 0);
        if (more) stageA(t1, 1, sb);
        mm(0);
        // P3: kk1 / mi 4-7
        asm volatile("s_barrier" ::: "memory");
        rdA(buf, 1, 1);
        if (more) stageB(t1, 1, sb);
        mm(1);
    }

    // epilogue: bias + store (C/D: col=lane&15, row=quad*4+r)
    float bv[4];
    #pragma unroll
    for (int ni = 0; ni < 4; ++ni)
        bv[ni] = bias[wn + ni * 16 + lrow];

    #pragma unroll
    for (int mi = 0; mi < 8; ++mi) {
        #pragma unroll
        for (int r = 0; r < 4; ++r) {
            const int row = by * BM + wm + mi * 16 + quad * 4 + r;
            float* o = out + (size_t)row * CO + wn + lrow;
            #pragma unroll
            for (int ni = 0; ni < 4; ++ni)
                o[ni * 16] = acc[mi][ni][r] + bv[ni];
        }
    }
}

extern "C" void kernel_launch(void* const* d_in, const int* in_sizes, int n_in,
                              void* d_out, int out_size, void* d_ws, size_t ws_size,
                              hipStream_t stream) {
    (void)in_sizes; (void)n_in; (void)out_size; (void)ws_size;
    const float* x    = (const float*)d_in[0];
    const float* w    = (const float*)d_in[1];
    const float* bias = (const float*)d_in[2];
    float* out = (float*)d_out;

    unsigned short* wt = (unsigned short*)d_ws;                     // bf16 [256][1152]
    unsigned short* xb = (unsigned short*)((char*)d_ws + XB_OFF);   // bf16 [32][58][58][128]

    prepass_kernel<<<dim3(WTBLK + XPBLK), dim3(256), 0, stream>>>(x, w, xb, wt);
    conv_gemm_kernel<<<dim3(GRID_M), dim3(512), 0, stream>>>(xb, wt, bias, out);
}